// Round 16
// baseline (2434.979 us; speedup 1.0000x reference)
//
#include <hip/hip_runtime.h>
#include <cstdio>
#include <cstdint>

// Problem constants
#define B_ 64
#define T_ 24
#define L_ 25          // T+1
#define E_ 512
#define H_ 1024
#define A_ 1024
#define V_ 32000
#define HCAT 5632      // A + E + 4H

// Split-K partial counts (KITERS=2 -> BK*2=256 K per split)
#define NKY_H 12       // 3072 / 256
#define NKY_Z 6        // 1536 / 256

typedef unsigned short u16;
typedef short bf16x8 __attribute__((ext_vector_type(8)));
typedef float f32x4 __attribute__((ext_vector_type(4)));

__device__ __forceinline__ u16 f2bf(float f) {
    union { float f; unsigned int u; } v; v.f = f;
    unsigned int u = v.u;
    unsigned int r = (u + 0x7FFFu + ((u >> 16) & 1u)) >> 16;
    return (u16)r;
}
__device__ __forceinline__ float bf2f(u16 h) {
    union { unsigned int u; float f; } v; v.u = ((unsigned int)h) << 16;
    return v.f;
}
__device__ __forceinline__ void splitbf(float a, u16& hi, u16& lo) {
    hi = f2bf(a);
    lo = f2bf(a - bf2f(hi));
}
__device__ __forceinline__ float sigf(float x) { return 1.f / (1.f + __expf(-x)); }

// global -> LDS direct DMA, 16B per lane; lds dest = wave-uniform base + lane*16
__device__ __forceinline__ void gload16(const u16* g, u16* l) {
    __builtin_amdgcn_global_load_lds(
        (const __attribute__((address_space(1))) unsigned int*)g,
        (__attribute__((address_space(3))) unsigned int*)l, 16, 0, 0);
}

// ---------------- Prologue kernels ----------------

__global__ void build_embeds(const float* __restrict__ features, const int* __restrict__ captions,
                             const float* __restrict__ emb, float* __restrict__ embeds,
                             float* __restrict__ mean_eT, u16* __restrict__ embsL2,
                             u16* __restrict__ embsA2) {
    int b = blockIdx.x; int e = threadIdx.x; // 512 threads
    float s = 0.f;
    for (int l = 0; l < L_; ++l) {
        float w;
        if (l == 0) w = features[b * E_ + e];
        else {
            int cap = captions[b * T_ + (l - 1)];
            w = emb[(size_t)cap * E_ + e];
        }
        embeds[(size_t)(b * L_ + l) * E_ + e] = w;
        s += w;
        u16 hi, lo; splitbf(w, hi, lo);
        size_t rl = (size_t)(b * L_ + l) * 1536;
        embsL2[rl + e] = hi; embsL2[rl + 512 + e] = lo; embsL2[rl + 1024 + e] = hi;
        if (l < T_) {
            size_t ra = (size_t)(l * 64 + b) * 1536;
            embsA2[ra + e] = hi; embsA2[ra + 512 + e] = lo; embsA2[ra + 1024 + e] = hi;
        }
    }
    mean_eT[e * B_ + b] = s * (1.f / 25.f);
}

// One kernel for ALL weight transforms (R8-proven).
__global__ __launch_bounds__(256) void prep_weights(
    const float* __restrict__ Wo, const float* __restrict__ Wd, const float* __restrict__ Wfb,
    const float* __restrict__ Wh, const float* __restrict__ Wi, const float* __restrict__ We,
    u16* __restrict__ WoT, u16* __restrict__ WcatT2, u16* __restrict__ WiT2a,
    u16* __restrict__ WiT2b, u16* __restrict__ WeT2) {
    __shared__ float tile[32][33];
    int id = blockIdx.x;
    int tid = threadIdx.x, tx = tid & 31, ty = tid >> 5;
    if (id < 32000) {
        int nx = id % 1000, ky = id / 1000;
        int n0 = nx * 32, k0 = ky * 32;
        for (int i = ty; i < 32; i += 8)
            tile[i][tx] = Wo[(size_t)(k0 + i) * V_ + n0 + tx];
        __syncthreads();
        for (int i = ty; i < 32; i += 8)
            WoT[(size_t)(n0 + i) * H_ + k0 + tx] = f2bf(tile[tx][i]);
        return;
    }
    id -= 32000;
    const float* W; u16* dst; int K, srcld, tilesx;
    if (id < 1024)      {             W = Wd;  dst = WcatT2;                        K = 1024; srcld = 1024; tilesx = 32; }
    else if (id < 1536) { id -= 1024; W = Wfb; dst = WcatT2 + (size_t)1024 * 3072;  K = 1024; srcld = 512;  tilesx = 16; }
    else if (id < 5632) { id -= 1536; W = Wh;  dst = WcatT2 + (size_t)1536 * 3072;  K = 1024; srcld = 4096; tilesx = 128; }
    else if (id < 7680) { id -= 5632; W = Wi;  dst = WiT2a;                         K = 512;  srcld = 4096; tilesx = 128; }
    else if (id < 9728) { id -= 7680; W = Wi + (size_t)512 * 4096; dst = WiT2b;     K = 512;  srcld = 4096; tilesx = 128; }
    else                { id -= 9728; W = We;  dst = WeT2;                          K = 512;  srcld = 1024; tilesx = 32; }
    int n0 = (id % tilesx) * 32, k0 = (id / tilesx) * 32;
    for (int i = ty; i < 32; i += 8)
        tile[i][tx] = W[(size_t)(k0 + i) * srcld + n0 + tx];
    __syncthreads();
    for (int i = ty; i < 32; i += 8) {
        float v = tile[tx][i];
        u16 hi, lo; splitbf(v, hi, lo);
        u16* d = dst + (size_t)(n0 + i) * (3 * K) + (k0 + tx);
        d[0] = hi; d[K] = hi; d[2 * K] = lo;
    }
}

__global__ __launch_bounds__(1024) void init_hc(const float* __restrict__ mean_eT,
                                                const float* __restrict__ Wih, const float* __restrict__ bih,
                                                const float* __restrict__ Wic, const float* __restrict__ bic,
                                                u16* __restrict__ h2, float* __restrict__ c) {
    int tid = threadIdx.x; int ny = tid & 15, r = tid >> 4;
    int col = blockIdx.x * 16 + ny;
    int cc = (col < H_) ? col : col - H_;
    const float* Wp = (col < H_) ? Wih : Wic;
    const float* bp = (col < H_) ? bih : bic;
    float acc = bp[cc];
    for (int k = 0; k < E_; ++k) acc += mean_eT[k * B_ + r] * Wp[(size_t)k * H_ + cc];
    if (col < H_) {
        u16 hi, lo; splitbf(acc, hi, lo);
        h2[(size_t)r * 3072 + cc] = hi;
        h2[(size_t)r * 3072 + 1024 + cc] = lo;
        h2[(size_t)r * 3072 + 2048 + cc] = hi;
    } else c[r * H_ + cc] = acc;
}

// ---------------- Generic split-bf16 MFMA GEMM (prologue: att1, P1) ----------------
template<int BM, int BN>
__global__ __launch_bounds__(256) void gemm_split(const u16* __restrict__ A2, const u16* __restrict__ B2T,
                                                  const float* __restrict__ bias, float* __restrict__ C,
                                                  int K3, int ldc) {
    constexpr int LDS = 40;
    __shared__ u16 As[BM * LDS];
    __shared__ u16 Bs[BN * LDS];
    constexpr int FM = BM / 32, FN = BN / 32;
    constexpr int ACH = BM / 64, BCH = BN / 64;
    int m0 = blockIdx.x * BM, n0 = blockIdx.y * BN;
    int tid = threadIdx.x, lane = tid & 63, wid = tid >> 6;
    int wm = wid >> 1, wn = wid & 1;

    f32x4 acc[FM][FN];
#pragma unroll
    for (int m = 0; m < FM; ++m)
#pragma unroll
        for (int n = 0; n < FN; ++n) acc[m][n] = (f32x4){0.f, 0.f, 0.f, 0.f};

    const u16* agp[ACH]; u16* asw[ACH];
    const u16* bgp[BCH]; u16* bsw[BCH];
#pragma unroll
    for (int i = 0; i < ACH; ++i) {
        int id = i * 256 + tid; int row = id >> 2, q = id & 3;
        agp[i] = A2 + (size_t)(m0 + row) * K3 + q * 8;
        asw[i] = As + row * LDS + q * 8;
    }
#pragma unroll
    for (int i = 0; i < BCH; ++i) {
        int id = i * 256 + tid; int row = id >> 2, q = id & 3;
        bgp[i] = B2T + (size_t)(n0 + row) * K3 + q * 8;
        bsw[i] = Bs + row * LDS + q * 8;
    }
    int rsel = lane & 15, kg = (lane >> 4) * 8;
    const u16* ard[FM]; const u16* brd[FN];
#pragma unroll
    for (int m = 0; m < FM; ++m) ard[m] = As + (wm * (BM / 2) + m * 16 + rsel) * LDS + kg;
#pragma unroll
    for (int n = 0; n < FN; ++n) brd[n] = Bs + (wn * (BN / 2) + n * 16 + rsel) * LDS + kg;

    uint4 ar[ACH], br[BCH];
#pragma unroll
    for (int i = 0; i < ACH; ++i) ar[i] = *(const uint4*)(agp[i]);
#pragma unroll
    for (int i = 0; i < BCH; ++i) br[i] = *(const uint4*)(bgp[i]);

    int nk = K3 / 32;
    for (int k = 0; k < nk; ++k) {
#pragma unroll
        for (int i = 0; i < ACH; ++i) *(uint4*)(asw[i]) = ar[i];
#pragma unroll
        for (int i = 0; i < BCH; ++i) *(uint4*)(bsw[i]) = br[i];
        __syncthreads();
        if (k + 1 < nk) {
            int kt = (k + 1) * 32;
#pragma unroll
            for (int i = 0; i < ACH; ++i) ar[i] = *(const uint4*)(agp[i] + kt);
#pragma unroll
            for (int i = 0; i < BCH; ++i) br[i] = *(const uint4*)(bgp[i] + kt);
        }
        bf16x8 aF[FM], bF[FN];
#pragma unroll
        for (int m = 0; m < FM; ++m) aF[m] = *(const bf16x8*)(ard[m]);
#pragma unroll
        for (int n = 0; n < FN; ++n) bF[n] = *(const bf16x8*)(brd[n]);
#pragma unroll
        for (int m = 0; m < FM; ++m)
#pragma unroll
            for (int n = 0; n < FN; ++n)
                acc[m][n] = __builtin_amdgcn_mfma_f32_16x16x32_bf16(aF[m], bF[n], acc[m][n], 0, 0, 0);
        __syncthreads();
    }

    int r4 = (lane >> 4) * 4, cn = lane & 15;
#pragma unroll
    for (int n = 0; n < FN; ++n) {
        int gcol = n0 + wn * (BN / 2) + n * 16 + cn;
        float bv = bias[gcol];
#pragma unroll
        for (int m = 0; m < FM; ++m) {
            int gr = m0 + wm * (BM / 2) + m * 16 + r4;
#pragma unroll
            for (int reg = 0; reg < 4; ++reg)
                C[(size_t)(gr + reg) * ldc + gcol] = acc[m][n][reg] + bv;
        }
    }
}

// ---------------- Split-K partial GEMM for the recurrence (R13-proven) ----------------
template<int KITERS>
__global__ __launch_bounds__(256, 2) void gemm_sk(const u16* __restrict__ A2, const u16* __restrict__ B2T,
                                                  float* __restrict__ part, int K3, int N) {
    constexpr int BK = 128;
    constexpr int LDS = BK + 8;
    __shared__ u16 As[64 * LDS];
    __shared__ u16 Bs[64 * LDS];
    int n0 = blockIdx.x * 64;
    int ky = blockIdx.y;
    int k0 = ky * (BK * KITERS);
    int tid = threadIdx.x, lane = tid & 63, wid = tid >> 6;
    int wm = wid >> 1, wn = wid & 1;

    f32x4 acc[2][2];
#pragma unroll
    for (int m = 0; m < 2; ++m)
#pragma unroll
        for (int n = 0; n < 2; ++n) acc[m][n] = (f32x4){0.f, 0.f, 0.f, 0.f};

    int srow = tid >> 4, scq = tid & 15;
    const u16* agp[4]; u16* asw[4];
    const u16* bgp[4]; u16* bsw[4];
#pragma unroll
    for (int i = 0; i < 4; ++i) {
        int row = srow + i * 16;
        agp[i] = A2 + (size_t)row * K3 + k0 + scq * 8;
        asw[i] = As + row * LDS + scq * 8;
        bgp[i] = B2T + (size_t)(n0 + row) * K3 + k0 + scq * 8;
        bsw[i] = Bs + row * LDS + scq * 8;
    }
    int rsel = lane & 15, kg = (lane >> 4) * 8;
    const u16* ard[2]; const u16* brd[2];
#pragma unroll
    for (int m = 0; m < 2; ++m) ard[m] = As + (wm * 32 + m * 16 + rsel) * LDS + kg;
#pragma unroll
    for (int n = 0; n < 2; ++n) brd[n] = Bs + (wn * 32 + n * 16 + rsel) * LDS + kg;

    uint4 ar[4], br[4];
#pragma unroll
    for (int i = 0; i < 4; ++i) { ar[i] = *(const uint4*)(agp[i]); br[i] = *(const uint4*)(bgp[i]); }

    for (int it = 0; it < KITERS; ++it) {
#pragma unroll
        for (int i = 0; i < 4; ++i) { *(uint4*)(asw[i]) = ar[i]; *(uint4*)(bsw[i]) = br[i]; }
        __syncthreads();
        if (it + 1 < KITERS) {
            int kt = (it + 1) * BK;
#pragma unroll
            for (int i = 0; i < 4; ++i) {
                ar[i] = *(const uint4*)(agp[i] + kt);
                br[i] = *(const uint4*)(bgp[i] + kt);
            }
        }
#pragma unroll
        for (int kk = 0; kk < BK / 32; ++kk) {
            bf16x8 aF[2], bF[2];
#pragma unroll
            for (int m = 0; m < 2; ++m) aF[m] = *(const bf16x8*)(ard[m] + kk * 32);
#pragma unroll
            for (int n = 0; n < 2; ++n) bF[n] = *(const bf16x8*)(brd[n] + kk * 32);
#pragma unroll
            for (int m = 0; m < 2; ++m)
#pragma unroll
                for (int n = 0; n < 2; ++n)
                    acc[m][n] = __builtin_amdgcn_mfma_f32_16x16x32_bf16(aF[m], bF[n], acc[m][n], 0, 0, 0);
        }
        __syncthreads();
    }

    float* p = part + (size_t)ky * 64 * N;
    int r4 = (lane >> 4) * 4, cn = lane & 15;
#pragma unroll
    for (int n = 0; n < 2; ++n) {
        int gcol = n0 + wn * 32 + n * 16 + cn;
#pragma unroll
        for (int m = 0; m < 2; ++m) {
            int gr = wm * 32 + m * 16 + r4;
#pragma unroll
            for (int reg = 0; reg < 4; ++reg)
                p[(size_t)(gr + reg) * N + gcol] = acc[m][n][reg];
        }
    }
}

// ---------------- Per-step kernels (R13-proven) ----------------

__global__ __launch_bounds__(256) void step_attn(const float* __restrict__ hpart, const float* __restrict__ att1,
                                                 const float* __restrict__ embeds, const float* __restrict__ va,
                                                 const float* __restrict__ bd, const float* __restrict__ bfb,
                                                 u16* __restrict__ x2s) {
    __shared__ float proj_s[1024], va_s[1024], sc_s[32], al_s[32];
    int b = blockIdx.x; int tid = threadIdx.x; int lane = tid & 63; int w = tid >> 6;
    for (int i = tid; i < 1024; i += 256) {
        float s = bd[i];
#pragma unroll
        for (int ky = 0; ky < NKY_H; ++ky) s += hpart[(size_t)ky * 64 * HCAT + b * HCAT + i];
        proj_s[i] = s; va_s[i] = va[i];
    }
    __syncthreads();
    for (int l = w; l < L_; l += 4) {
        const float* arow = att1 + (size_t)(b * L_ + l) * A_;
        float p = 0.f;
        for (int a = lane; a < A_; a += 64) {
            float v = arow[a] + proj_s[a];
            p += fmaxf(v, 0.f) * va_s[a];
        }
        for (int off = 32; off; off >>= 1) p += __shfl_down(p, off);
        if (lane == 0) sc_s[l] = p;
    }
    __syncthreads();
    if (w == 0) {
        float s = (lane < L_) ? sc_s[lane] : -1e30f;
        float m = s;
        for (int off = 32; off; off >>= 1) m = fmaxf(m, __shfl_xor(m, off));
        float e = (lane < L_) ? __expf(s - m) : 0.f;
        float sum = e;
        for (int off = 32; off; off >>= 1) sum += __shfl_xor(sum, off);
        if (lane < L_) al_s[lane] = e / sum;
    }
    __syncthreads();
    for (int e = tid; e < E_; e += 256) {
        float aw = 0.f;
        for (int l = 0; l < L_; ++l) aw += al_s[l] * embeds[(size_t)(b * L_ + l) * E_ + e];
        float gp = bfb[e];
#pragma unroll
        for (int ky = 0; ky < NKY_H; ++ky) gp += hpart[(size_t)ky * 64 * HCAT + b * HCAT + 1024 + e];
        float v = sigf(gp) * aw;
        u16 hi, lo; splitbf(v, hi, lo);
        x2s[(size_t)b * 1536 + e] = hi;
        x2s[(size_t)b * 1536 + 512 + e] = lo;
        x2s[(size_t)b * 1536 + 1024 + e] = hi;
    }
}

__global__ __launch_bounds__(256) void step_lstm(const float* __restrict__ zpart, const float* __restrict__ P1,
                                                 const float* __restrict__ hpart, float* __restrict__ c,
                                                 u16* __restrict__ h2, u16* __restrict__ hs_bf, int t) {
    int idx = blockIdx.x * 256 + threadIdx.x; // 0..65535
    int b = idx >> 10, n = idx & 1023;
    float zv[4];
#pragma unroll
    for (int g = 0; g < 4; ++g) {
        int col = g * 1024 + n;
        float s = P1[(size_t)(t * 64 + b) * 4096 + col];
#pragma unroll
        for (int ky = 0; ky < NKY_Z; ++ky) s += zpart[(size_t)ky * 64 * 4096 + b * 4096 + col];
#pragma unroll
        for (int ky = 0; ky < NKY_H; ++ky) s += hpart[(size_t)ky * 64 * HCAT + b * HCAT + 1536 + col];
        zv[g] = s;
    }
    float cold = c[b * H_ + n];
    float cnew = sigf(zv[1]) * cold + sigf(zv[0]) * tanhf(zv[2]);
    float hh = sigf(zv[3]) * tanhf(cnew);
    c[b * H_ + n] = cnew;
    u16 hi, lo; splitbf(hh, hi, lo);
    h2[(size_t)b * 3072 + n] = hi;
    h2[(size_t)b * 3072 + 1024 + n] = lo;
    h2[(size_t)b * 3072 + 2048 + n] = hi;
    hs_bf[(size_t)(t * 64 + b) * 1024 + n] = f2bf(hh);
}

// ---------------- Final logits GEMM — BK=32, DMA + both-sides chunk swizzle, XCD swizzle ----------------
// LDS linear [128][32] u16. Chunk c (16B) of row r stored at pos c ^ ((r>>1)&3):
// DMA source pre-swizzled, read side applies same XOR -> 2-way banks (free).
#define BMG 128
#define BNG 128
#define NWG_M (T_ * B_ / BMG)    // 12
#define NWG_N (V_ / BNG)         // 250
#define NWG (NWG_M * NWG_N)      // 3000 = 8 * 375

__global__ __launch_bounds__(256) void gemm_logits(const u16* __restrict__ Abf, const u16* __restrict__ Bbf,
                                                   const float* __restrict__ bo, float* __restrict__ out) {
    __shared__ u16 As[BMG * 32];
    __shared__ u16 Bs[BNG * 32];
    int lid = blockIdx.x;
    int wg = (lid & 7) * (NWG / 8) + (lid >> 3);
    int m0 = (wg % NWG_M) * BMG;
    int n0 = (wg / NWG_M) * BNG;
    int tid = threadIdx.x; int lane = tid & 63; int wid = tid >> 6;
    int wm = wid >> 1, wn = wid & 1;

    f32x4 acc[4][4];
#pragma unroll
    for (int m = 0; m < 4; ++m)
#pragma unroll
        for (int n = 0; n < 4; ++n) acc[m][n] = (f32x4){0.f, 0.f, 0.f, 0.f};

    // DMA: wave w rows w*32..+31 in two issues of 16 rows; lane l: row l>>2, dest pos l&3.
    // Source chunk = (l&3) ^ ((row>>1)&3). (row>>1)&3 identical for both issues (+16 rows).
    int rowoff = lane >> 2;                       // 0..15
    int gchunk = (lane & 3) ^ ((rowoff >> 1) & 3);
    int srow = wid * 32 + rowoff;
    const u16* agA0 = Abf + (size_t)(m0 + srow) * H_ + gchunk * 8;
    const u16* agA1 = agA0 + (size_t)16 * H_;
    const u16* agB0 = Bbf + (size_t)(n0 + srow) * H_ + gchunk * 8;
    const u16* agB1 = agB0 + (size_t)16 * H_;
    u16* lA0 = As + (wid * 32) * 32;
    u16* lA1 = As + (wid * 32 + 16) * 32;
    u16* lB0 = Bs + (wid * 32) * 32;
    u16* lB1 = Bs + (wid * 32 + 16) * 32;

    int rsel = (lane & 15);
    int q = lane >> 4;                            // logical 16B chunk 0..3
    int pos = q ^ ((rsel >> 1) & 3);              // physical chunk after swizzle
    const u16* ard[4]; const u16* brd[4];
#pragma unroll
    for (int m = 0; m < 4; ++m) {
        ard[m] = As + (wm * 64 + m * 16 + rsel) * 32 + pos * 8;
        brd[m] = Bs + (wn * 64 + m * 16 + rsel) * 32 + pos * 8;
    }

    for (int kt = 0; kt < H_; kt += 32) {
        gload16(agA0 + kt, lA0);
        gload16(agA1 + kt, lA1);
        gload16(agB0 + kt, lB0);
        gload16(agB1 + kt, lB1);
        __syncthreads();
        bf16x8 aF[4], bF[4];
#pragma unroll
        for (int m = 0; m < 4; ++m) aF[m] = *(const bf16x8*)(ard[m]);
#pragma unroll
        for (int n = 0; n < 4; ++n) bF[n] = *(const bf16x8*)(brd[n]);
#pragma unroll
        for (int m = 0; m < 4; ++m)
#pragma unroll
            for (int n = 0; n < 4; ++n)
                acc[m][n] = __builtin_amdgcn_mfma_f32_16x16x32_bf16(aF[m], bF[n], acc[m][n], 0, 0, 0);
        __syncthreads();
    }

    int r4 = (lane >> 4) * 4;
    int cn = lane & 15;
#pragma unroll
    for (int n = 0; n < 4; ++n) {
        int gn = n0 + wn * 64 + n * 16 + cn;
        float bv = bo[gn];
#pragma unroll
        for (int m = 0; m < 4; ++m) {
            int gmb = m0 + wm * 64 + m * 16 + r4;
#pragma unroll
            for (int reg = 0; reg < 4; ++reg) {
                int gm = gmb + reg;
                int b = gm & 63, t = gm >> 6;
                out[(size_t)(b * T_ + t) * V_ + gn] = acc[m][n][reg] + bv;
            }
        }
    }
}

// ---------------- Host launch ----------------
extern "C" void kernel_launch(void* const* d_in, const int* in_sizes, int n_in,
                              void* d_out, int out_size, void* d_ws, size_t ws_size,
                              hipStream_t stream) {
    const float* features = (const float*)d_in[0];
    const int*   captions = (const int*)d_in[1];
    const float* emb = (const float*)d_in[3];
    const float* We  = (const float*)d_in[4];
    const float* be  = (const float*)d_in[5];
    const float* Wd  = (const float*)d_in[6];
    const float* bd  = (const float*)d_in[7];
    const float* va  = (const float*)d_in[8];
    const float* Wih = (const float*)d_in[10];
    const float* bih = (const float*)d_in[11];
    const float* Wic = (const float*)d_in[12];
    const float* bic = (const float*)d_in[13];
    const float* Wfb = (const float*)d_in[14];
    const float* bfb = (const float*)d_in[15];
    const float* Wi  = (const float*)d_in[16];
    const float* Wh  = (const float*)d_in[17];
    const float* bl  = (const float*)d_in[18];
    const float* Wo  = (const float*)d_in[19];
    const float* bo  = (const float*)d_in[20];
    float* out = (float*)d_out;

    // d_ws allocations
    char* ws = (char*)d_ws; size_t wo = 0;
    auto walloc = [&](size_t bytes) -> void* {
        void* p = ws + wo; wo += (bytes + 255) & ~(size_t)255; return p;
    };
    float* embeds  = (float*)walloc((size_t)B_ * L_ * E_ * 4);
    float* mean_eT = (float*)walloc((size_t)E_ * B_ * 4);
    u16*   embsL2  = (u16*)walloc((size_t)B_ * L_ * 1536 * 2);
    u16*   embsA2  = (u16*)walloc((size_t)T_ * B_ * 1536 * 2);
    u16*   h2      = (u16*)walloc((size_t)B_ * 3072 * 2);
    float* c       = (float*)walloc((size_t)B_ * H_ * 4);
    u16*   x2s     = (u16*)walloc((size_t)B_ * 1536 * 2);
    u16*   hs_bf   = (u16*)walloc((size_t)T_ * B_ * H_ * 2);
    u16*   WoT     = (u16*)walloc((size_t)V_ * H_ * 2);
    float* hpart   = (float*)walloc((size_t)NKY_H * B_ * HCAT * 4);
    float* zpart   = (float*)walloc((size_t)NKY_Z * B_ * 4096 * 4);
    if (wo > ws_size) {
        fprintf(stderr, "kernel_launch: ws too small: need %zu have %zu\n", wo, ws_size);
        return;
    }

    // d_out aliased scratch (dead before gemm_logits writes out)
    char* ob = (char*)d_out; size_t oo = 0;
    auto oalloc = [&](size_t bytes) -> void* {
        void* p = ob + oo; oo += (bytes + 255) & ~(size_t)255; return p;
    };
    float* P1     = (float*)oalloc((size_t)T_ * B_ * 4096 * 4);   // 25.2 MB
    u16*   WcatT2 = (u16*)oalloc((size_t)HCAT * 3072 * 2);        // 34.6 MB
    u16*   WiT2a  = (u16*)oalloc((size_t)4096 * 1536 * 2);        // 12.6 MB
    u16*   WiT2b  = (u16*)oalloc((size_t)4096 * 1536 * 2);        // 12.6 MB
    u16*   WeT2   = (u16*)oalloc((size_t)1024 * 1536 * 2);        //  3.1 MB
    float* att1   = (float*)oalloc((size_t)B_ * L_ * A_ * 4);     //  6.6 MB

    // ---- prologue ----
    build_embeds<<<B_, E_, 0, stream>>>(features, captions, emb, embeds, mean_eT, embsL2, embsA2);
    prep_weights<<<32000 + 10240, 256, 0, stream>>>(Wo, Wd, Wfb, Wh, Wi, We,
                                                    WoT, WcatT2, WiT2a, WiT2b, WeT2);
    init_hc<<<2 * H_ / 16, 1024, 0, stream>>>(mean_eT, Wih, bih, Wic, bic, h2, c);
    gemm_split<64, 64><<<dim3(1600 / 64, 1024 / 64), 256, 0, stream>>>(embsL2, WeT2, be, att1, 1536, 1024);
    gemm_split<128, 64><<<dim3(1536 / 128, 4096 / 64), 256, 0, stream>>>(embsA2, WiT2a, bl, P1, 1536, 4096);

    // ---- recurrence: 4 dispatches/step, KITERS=2 (R13-proven) ----
    for (int t = 0; t < T_; ++t) {
        gemm_sk<2><<<dim3(HCAT / 64, NKY_H), 256, 0, stream>>>(h2, WcatT2, hpart, 3072, HCAT);
        step_attn<<<B_, 256, 0, stream>>>(hpart, att1, embeds, va, bd, bfb, x2s);
        gemm_sk<2><<<dim3(4096 / 64, NKY_Z), 256, 0, stream>>>(x2s, WiT2b, zpart, 1536, 4096);
        step_lstm<<<B_ * H_ / 256, 256, 0, stream>>>(zpart, P1, hpart, c, h2, hs_bf, t);
    }

    // ---- logits ----
    gemm_logits<<<NWG, 256, 0, stream>>>(hs_bf, WoT, bo, out);
}